// Round 14
// baseline (142.523 us; speedup 1.0000x reference)
//
#include <hip/hip_runtime.h>
#include <hip/hip_bf16.h>
#include <hip/hip_fp16.h>

// Sparse gather-FFN. R13 (2 row-groups, 256T, 2 blk/CU) won on barriers
// (-2.5us steady) but lost TLP (8 waves/CU, worst-case 84-91us).
// R14: same 16-rows/block + one-barrier-per-16-rows, but 512 threads:
// half-block 0-255 serves group A, 256-511 group B. Per-thread work =
// R12's (4 gathers/quartet, VGPR ~50), waves/CU = 16 (vs R13's 8).
// idx/w loads duplicated across halves -> same address, L1 broadcast.
// DS read total unchanged; conflicts expected exactly 1.654e7.

#define NB   32768
#define NIN  128
#define NL   8
#define NW   256
#define NK   16
#define RPB  16                       // rows per block = 2 groups x 8
#define STORED (NIN + (NL - 1) * NW)  // 1920 features per group
#define NPARAM (NL * NW * NK)         // 32768 (l,u,k) entries

typedef __fp16 fp16v2 __attribute__((ext_vector_type(2)));

__device__ __forceinline__ unsigned pk16(float a, float b) {
    fp16v2 p = __builtin_amdgcn_cvt_pkrtz(a, b);   // v_cvt_pkrtz_f16_f32
    return __builtin_bit_cast(unsigned, p);
}

__device__ __forceinline__ __half2 as_h2(unsigned u) {
    return __builtin_bit_cast(__half2, u);
}

__device__ __forceinline__ float fast_sigmoid(float x) {
    return __builtin_amdgcn_rcpf(1.0f + __expf(-x));
}

// 8 row-MACs from one 16B packed-f16 word: 4x v_pk_fma_f16
__device__ __forceinline__ void fma_feat(__half2 acc[4], __half2 w2, uint4 p) {
    acc[0] = __hfma2(as_h2(p.x), w2, acc[0]);
    acc[1] = __hfma2(as_h2(p.y), w2, acc[1]);
    acc[2] = __hfma2(as_h2(p.z), w2, acc[2]);
    acc[3] = __hfma2(as_h2(p.w), w2, acc[3]);
}

template <bool PRE>
__global__ __launch_bounds__(512, 2)
void ffn_gather_kernel(const float* __restrict__ inputs,
                       const float* __restrict__ weights,
                       const float* __restrict__ biases,
                       const int*   __restrict__ edge_idx,
                       const int*   __restrict__ idxb,   // pre-scaled byte offs
                       const unsigned* __restrict__ wpk, // packed (w,w) f16
                       float* __restrict__ out)
{
    __shared__ uint4 vals[2][STORED];  // [grp][f] = 8 f16 rows of feature f

    const int tid = threadIdx.x;                     // 0..511
    const int grp = tid >> 8;                        // 0 = A, 1 = B
    const int t   = tid & 255;                       // unit id
    const long long row0 = (long long)blockIdx.x * RPB + grp * 8;
    const char* vbase = (const char*)vals[grp];

    // ---- stage 128 input features x 8 rows for this half's group ----
    if (t < NIN) {
        float v[8];
        #pragma unroll
        for (int r = 0; r < 8; ++r) v[r] = inputs[(row0 + r) * NIN + t];
        uint4 p;
        p.x = pk16(v[0], v[1]);
        p.y = pk16(v[2], v[3]);
        p.z = pk16(v[4], v[5]);
        p.w = pk16(v[6], v[7]);
        vals[grp][t] = p;
    }
    __syncthreads();

    // ---- layers ----
    #pragma unroll
    for (int l = 0; l < NL; ++l) {
        const int base = (l * NW + t) * NK;

        const float b = biases[l * NW + t];
        __half2 acc[4];
        const __half2 bb = __float2half2_rn(b);
        #pragma unroll
        for (int j = 0; j < 4; ++j) acc[j] = bb;

        #pragma unroll
        for (int kk = 0; kk < NK / 4; ++kk) {
            int4 o4;          // byte offsets into this group's vals
            __half2 w0, w1, w2, w3;
            if (PRE) {
                o4 = ((const int4*)(idxb + base))[kk];
                uint4 wp = ((const uint4*)(wpk + base))[kk];
                w0 = as_h2(wp.x); w1 = as_h2(wp.y);
                w2 = as_h2(wp.z); w3 = as_h2(wp.w);
            } else {
                int4 i4 = ((const int4*)(edge_idx + base))[kk];
                o4.x = i4.x << 4; o4.y = i4.y << 4;
                o4.z = i4.z << 4; o4.w = i4.w << 4;
                float4 w4 = ((const float4*)(weights + base))[kk];
                w0 = __float2half2_rn(w4.x);
                w1 = __float2half2_rn(w4.y);
                w2 = __float2half2_rn(w4.z);
                w3 = __float2half2_rn(w4.w);
            }
            const uint4 p0 = *(const uint4*)(vbase + o4.x);
            const uint4 p1 = *(const uint4*)(vbase + o4.y);
            const uint4 p2 = *(const uint4*)(vbase + o4.z);
            const uint4 p3 = *(const uint4*)(vbase + o4.w);
            fma_feat(acc, w0, p0);
            fma_feat(acc, w1, p1);
            fma_feat(acc, w2, p2);
            fma_feat(acc, w3, p3);
        }

        float s[8];
        #pragma unroll
        for (int j = 0; j < 4; ++j) {
            s[2 * j + 0] = fast_sigmoid(__low2float(acc[j]));
            s[2 * j + 1] = fast_sigmoid(__high2float(acc[j]));
        }

        if (l < NL - 1) {
            uint4 p;
            p.x = pk16(s[0], s[1]);
            p.y = pk16(s[2], s[3]);
            p.z = pk16(s[4], s[5]);
            p.w = pk16(s[6], s[7]);
            vals[grp][NIN + l * NW + t] = p;
            __syncthreads();           // one barrier per 16 rows per layer
        } else {
            #pragma unroll
            for (int r = 0; r < 8; ++r)
                out[(row0 + r) * NW + t] = s[r];
        }
    }
}

// trivial pre-pass: byte-offset indices + packed (w,w) f16 weights.
__global__ __launch_bounds__(256)
void prepass_kernel(const float* __restrict__ weights,
                    const int* __restrict__ edge_idx,
                    int* __restrict__ idxb,
                    unsigned* __restrict__ wpk)
{
    const int i = blockIdx.x * 256 + threadIdx.x;   // 0..32767
    idxb[i] = edge_idx[i] << 4;
    const float w = weights[i];
    wpk[i] = pk16(w, w);
}

extern "C" void kernel_launch(void* const* d_in, const int* in_sizes, int n_in,
                              void* d_out, int out_size, void* d_ws, size_t ws_size,
                              hipStream_t stream)
{
    const float* inputs   = (const float*)d_in[0];
    const float* weights  = (const float*)d_in[1];
    const float* biases   = (const float*)d_in[2];
    const int*   edge_idx = (const int*)d_in[3];
    float* out = (float*)d_out;

    dim3 grid(NB / RPB);   // 2048
    dim3 block(512);

    const size_t need = (size_t)NPARAM * 4 * 2;     // 256 KB
    if (ws_size >= need) {
        int*      idxb = (int*)d_ws;
        unsigned* wpk  = (unsigned*)((char*)d_ws + (size_t)NPARAM * 4);
        prepass_kernel<<<NPARAM / 256, 256, 0, stream>>>(weights, edge_idx,
                                                         idxb, wpk);
        ffn_gather_kernel<true><<<grid, block, 0, stream>>>(
            inputs, weights, biases, edge_idx, idxb, wpk, out);
    } else {
        ffn_gather_kernel<false><<<grid, block, 0, stream>>>(
            inputs, weights, biases, edge_idx, nullptr, nullptr, out);
    }
}

// Round 15
// 133.625 us; speedup vs baseline: 1.0666x; 1.0666x over previous
//
#include <hip/hip_runtime.h>
#include <hip/hip_bf16.h>
#include <hip/hip_fp16.h>

// Sparse gather-FFN — FINAL (R13 champion, reverted after R14's 512T regress).
// Structure: 16 rows/block as two 8-row f16 groups (valsA/valsB, 61.4KB LDS,
// 2 blk/CU); each thread loads idx/w once per quartet and serves both groups
// (8 independent ds_read_b128 in flight); one barrier per 16 rows per layer.
// Ceiling model: DS pipe ~68us/CU (8192 wave b128 x 12cyc + 27us structural
// octet conflicts, irreducible per R7-R9); steady main ~74us = 92% of model.
// VALU (27us) and HBM (7%) fully hidden. fp8 storage failed accuracy (R11);
// schedule-order conflict shaping has zero dur coupling (R7-R9).

#define NB   32768
#define NIN  128
#define NL   8
#define NW   256
#define NK   16
#define RPB  16                       // rows per block = 2 groups x 8
#define STORED (NIN + (NL - 1) * NW)  // 1920 features per group
#define NPARAM (NL * NW * NK)         // 32768 (l,u,k) entries

typedef __fp16 fp16v2 __attribute__((ext_vector_type(2)));

__device__ __forceinline__ unsigned pk16(float a, float b) {
    fp16v2 p = __builtin_amdgcn_cvt_pkrtz(a, b);   // v_cvt_pkrtz_f16_f32
    return __builtin_bit_cast(unsigned, p);
}

__device__ __forceinline__ __half2 as_h2(unsigned u) {
    return __builtin_bit_cast(__half2, u);
}

__device__ __forceinline__ float fast_sigmoid(float x) {
    return __builtin_amdgcn_rcpf(1.0f + __expf(-x));
}

// 8 row-MACs from one 16B packed-f16 word: 4x v_pk_fma_f16
__device__ __forceinline__ void fma_feat(__half2 acc[4], __half2 w2, uint4 p) {
    acc[0] = __hfma2(as_h2(p.x), w2, acc[0]);
    acc[1] = __hfma2(as_h2(p.y), w2, acc[1]);
    acc[2] = __hfma2(as_h2(p.z), w2, acc[2]);
    acc[3] = __hfma2(as_h2(p.w), w2, acc[3]);
}

template <bool PRE>
__global__ __launch_bounds__(256, 2)
void ffn_gather_kernel(const float* __restrict__ inputs,
                       const float* __restrict__ weights,
                       const float* __restrict__ biases,
                       const int*   __restrict__ edge_idx,
                       const int*   __restrict__ idxb,   // pre-scaled byte offs
                       const unsigned* __restrict__ wpk, // packed (w,w) f16
                       float* __restrict__ out)
{
    __shared__ uint4 valsA[STORED];   // group A: rows row0..row0+7
    __shared__ uint4 valsB[STORED];   // group B: rows row0+8..row0+15

    const int t = threadIdx.x;                       // 0..255, unit id
    const long long row0 = (long long)blockIdx.x * RPB;
    const char* vbaseA = (const char*)valsA;
    const char* vbaseB = (const char*)valsB;

    // ---- stage 128 input features x 16 rows: t<128 -> A, t>=128 -> B ----
    {
        const int f = t & 127;
        const long long r0 = row0 + ((t >> 7) << 3);   // +0 (A) or +8 (B)
        float v[8];
        #pragma unroll
        for (int r = 0; r < 8; ++r) v[r] = inputs[(r0 + r) * NIN + f];
        uint4 p;
        p.x = pk16(v[0], v[1]);
        p.y = pk16(v[2], v[3]);
        p.z = pk16(v[4], v[5]);
        p.w = pk16(v[6], v[7]);
        if (t < NIN) valsA[f] = p; else valsB[f] = p;
    }
    __syncthreads();

    // ---- layers ----
    #pragma unroll
    for (int l = 0; l < NL; ++l) {
        const int base = (l * NW + t) * NK;

        const float b = biases[l * NW + t];
        __half2 accA[4], accB[4];
        const __half2 bb = __float2half2_rn(b);
        #pragma unroll
        for (int j = 0; j < 4; ++j) { accA[j] = bb; accB[j] = bb; }

        #pragma unroll
        for (int kk = 0; kk < NK / 4; ++kk) {
            int4 o4;          // byte offsets into vals (shared by A and B!)
            __half2 w0, w1, w2, w3;
            if (PRE) {
                o4 = ((const int4*)(idxb + base))[kk];
                uint4 wp = ((const uint4*)(wpk + base))[kk];
                w0 = as_h2(wp.x); w1 = as_h2(wp.y);
                w2 = as_h2(wp.z); w3 = as_h2(wp.w);
            } else {
                int4 i4 = ((const int4*)(edge_idx + base))[kk];
                o4.x = i4.x << 4; o4.y = i4.y << 4;
                o4.z = i4.z << 4; o4.w = i4.w << 4;
                float4 w4 = ((const float4*)(weights + base))[kk];
                w0 = __float2half2_rn(w4.x);
                w1 = __float2half2_rn(w4.y);
                w2 = __float2half2_rn(w4.z);
                w3 = __float2half2_rn(w4.w);
            }
            // 8 independent gathers (two per feature, groups A+B)
            const uint4 a0 = *(const uint4*)(vbaseA + o4.x);
            const uint4 b0 = *(const uint4*)(vbaseB + o4.x);
            const uint4 a1 = *(const uint4*)(vbaseA + o4.y);
            const uint4 b1 = *(const uint4*)(vbaseB + o4.y);
            const uint4 a2 = *(const uint4*)(vbaseA + o4.z);
            const uint4 b2 = *(const uint4*)(vbaseB + o4.z);
            const uint4 a3 = *(const uint4*)(vbaseA + o4.w);
            const uint4 b3 = *(const uint4*)(vbaseB + o4.w);
            fma_feat(accA, w0, a0);
            fma_feat(accB, w0, b0);
            fma_feat(accA, w1, a1);
            fma_feat(accB, w1, b1);
            fma_feat(accA, w2, a2);
            fma_feat(accB, w2, b2);
            fma_feat(accA, w3, a3);
            fma_feat(accB, w3, b3);
        }

        float sA[8], sB[8];
        #pragma unroll
        for (int j = 0; j < 4; ++j) {
            sA[2 * j + 0] = fast_sigmoid(__low2float(accA[j]));
            sA[2 * j + 1] = fast_sigmoid(__high2float(accA[j]));
            sB[2 * j + 0] = fast_sigmoid(__low2float(accB[j]));
            sB[2 * j + 1] = fast_sigmoid(__high2float(accB[j]));
        }

        if (l < NL - 1) {
            uint4 pA, pB;
            pA.x = pk16(sA[0], sA[1]); pA.y = pk16(sA[2], sA[3]);
            pA.z = pk16(sA[4], sA[5]); pA.w = pk16(sA[6], sA[7]);
            pB.x = pk16(sB[0], sB[1]); pB.y = pk16(sB[2], sB[3]);
            pB.z = pk16(sB[4], sB[5]); pB.w = pk16(sB[6], sB[7]);
            valsA[NIN + l * NW + t] = pA;
            valsB[NIN + l * NW + t] = pB;
            __syncthreads();           // ONE barrier per 16 rows per layer
        } else {
            #pragma unroll
            for (int r = 0; r < 8; ++r) {
                out[(row0 + r) * NW + t]     = sA[r];
                out[(row0 + 8 + r) * NW + t] = sB[r];
            }
        }
    }
}

// trivial pre-pass: byte-offset indices + packed (w,w) f16 weights.
__global__ __launch_bounds__(256)
void prepass_kernel(const float* __restrict__ weights,
                    const int* __restrict__ edge_idx,
                    int* __restrict__ idxb,
                    unsigned* __restrict__ wpk)
{
    const int i = blockIdx.x * 256 + threadIdx.x;   // 0..32767
    idxb[i] = edge_idx[i] << 4;
    const float w = weights[i];
    wpk[i] = pk16(w, w);
}

extern "C" void kernel_launch(void* const* d_in, const int* in_sizes, int n_in,
                              void* d_out, int out_size, void* d_ws, size_t ws_size,
                              hipStream_t stream)
{
    const float* inputs   = (const float*)d_in[0];
    const float* weights  = (const float*)d_in[1];
    const float* biases   = (const float*)d_in[2];
    const int*   edge_idx = (const int*)d_in[3];
    float* out = (float*)d_out;

    dim3 grid(NB / RPB);   // 2048
    dim3 block(NW);        // 256

    const size_t need = (size_t)NPARAM * 4 * 2;     // 256 KB
    if (ws_size >= need) {
        int*      idxb = (int*)d_ws;
        unsigned* wpk  = (unsigned*)((char*)d_ws + (size_t)NPARAM * 4);
        prepass_kernel<<<NPARAM / 256, 256, 0, stream>>>(weights, edge_idx,
                                                         idxb, wpk);
        ffn_gather_kernel<true><<<grid, block, 0, stream>>>(
            inputs, weights, biases, edge_idx, idxb, wpk, out);
    } else {
        ffn_gather_kernel<false><<<grid, block, 0, stream>>>(
            inputs, weights, biases, edge_idx, nullptr, nullptr, out);
    }
}